// Round 3
// baseline (377.656 us; speedup 1.0000x reference)
//
#include <hip/hip_runtime.h>

#define B_    8
#define N_    8192
#define M_    1024
#define C1_   256
#define C2_   512
#define CIN_  768
#define CMID_ 256
#define COUT_ 256

typedef __attribute__((ext_vector_type(8))) __bf16 bf16x8;           // 4 VGPRs, MFMA A/B frag
typedef __attribute__((ext_vector_type(4))) float f32x4;             // MFMA C/D frag
typedef __attribute__((ext_vector_type(4))) unsigned short u16x4;
typedef __attribute__((ext_vector_type(8))) unsigned short u16x8;

__device__ __forceinline__ unsigned short f2bf(float f) {
  union { float f; unsigned u; } v; v.f = f;
  unsigned r = v.u + 0x7FFFu + ((v.u >> 16) & 1u);   // RNE
  return (unsigned short)(r >> 16);
}
__device__ __forceinline__ float bf2f(unsigned short h) {
  union { unsigned u; float f; } v; v.u = ((unsigned)h) << 16; return v.f;
}

// async global -> LDS, 16B per lane per wave-instruction (dest = uniform base + lane*16)
__device__ __forceinline__ void gload16(const void* g, void* l) {
  __builtin_amdgcn_global_load_lds((const __attribute__((address_space(1))) unsigned int*)g,
                                   (__attribute__((address_space(3))) unsigned int*)l, 16, 0, 0);
}

// ---------------- small utility kernels ----------------

__global__ void k_zero(float* p, int n) {
  int i = blockIdx.x * 256 + threadIdx.x;
  if (i < n) p[i] = 0.f;
}

__global__ void k_cast(const float* __restrict__ in, unsigned short* __restrict__ out, int n) {
  int i = blockIdx.x * 256 + threadIdx.x;
  if (i < n) out[i] = f2bf(in[i]);
}

// known_feats (B, C2, M) f32 -> kft (B, M, C2) f32
__global__ void k_tr_kf(const float* __restrict__ in, float* __restrict__ out) {
  __shared__ float t[32][33];
  int b = blockIdx.z;
  int c0 = blockIdx.x * 32, m0 = blockIdx.y * 32;
  int tx = threadIdx.x, ty = threadIdx.y;
  const float* ip = in + ((size_t)b * C2_ + c0) * M_ + m0;
#pragma unroll
  for (int i = 0; i < 32; i += 8) t[ty + i][tx] = ip[(size_t)(ty + i) * M_ + tx];
  __syncthreads();
  float* op = out + ((size_t)b * M_ + m0) * C2_ + c0;
#pragma unroll
  for (int i = 0; i < 32; i += 8) op[(size_t)(ty + i) * C2_ + tx] = t[tx][ty + i];
}

// unknow_feats (B, C1, N) f32 -> xt[b][n][0:256] bf16 (row stride CIN_)
__global__ void k_tr_uf(const float* __restrict__ in, unsigned short* __restrict__ out) {
  __shared__ float t[32][33];
  int b = blockIdx.z;
  int c0 = blockIdx.x * 32, n0 = blockIdx.y * 32;
  int tx = threadIdx.x, ty = threadIdx.y;
  const float* ip = in + ((size_t)b * C1_ + c0) * N_ + n0;
#pragma unroll
  for (int i = 0; i < 32; i += 8) t[ty + i][tx] = ip[(size_t)(ty + i) * N_ + tx];
  __syncthreads();
  unsigned short* op = out + ((size_t)b * N_ + n0) * CIN_ + c0;
#pragma unroll
  for (int i = 0; i < 32; i += 8) op[(size_t)(ty + i) * CIN_ + tx] = f2bf(t[tx][ty + i]);
}

// ---------------- three_nn: exact fp32 (d, idx)-lex semantics, 8 lanes/query ----------------

__device__ __forceinline__ void ins3(float db, int ib, float& d0, int& i0,
                                     float& d1, int& i1, float& d2, int& i2) {
  if (db < d2 || (db == d2 && ib < i2)) {
    if (db < d1 || (db == d1 && ib < i1)) {
      d2 = d1; i2 = i1;
      if (db < d0 || (db == d0 && ib < i0)) { d1 = d0; i1 = i0; d0 = db; i0 = ib; }
      else                                  { d1 = db; i1 = ib; }
    } else { d2 = db; i2 = ib; }
  }
}

__global__ __launch_bounds__(256) void k_three_nn(const float* __restrict__ unknown,
                                                  const float* __restrict__ known,
                                                  int* __restrict__ idx, float* __restrict__ wgt) {
  __shared__ __align__(16) float kpts[M_][4];
  int b = blockIdx.x >> 8;
  int n0 = (blockIdx.x & 255) << 5;
  for (int i = threadIdx.x; i < M_; i += 256) {
    const float* kp = known + ((size_t)b * M_ + i) * 3;
    kpts[i][0] = kp[0]; kpts[i][1] = kp[1]; kpts[i][2] = kp[2];
  }
  __syncthreads();
  const int l = threadIdx.x & 63;
  const int j = l & 7;
  const int q = ((threadIdx.x >> 6) << 3) + (l >> 3);
  const int n = n0 + q;
  const float* up = unknown + ((size_t)b * N_ + n) * 3;
  float ux = up[0], uy = up[1], uz = up[2];
  float d0 = 1e30f, d1 = 1e30f, d2v = 1e30f;
  int i0 = 0, i1 = 0, i2 = 0;
  for (int t = 0; t < 128; ++t) {
    int i = t * 8 + j;
    f32x4 p = *(const f32x4*)kpts[i];
    float dx = __fsub_rn(ux, p[0]);
    float dy = __fsub_rn(uy, p[1]);
    float dz = __fsub_rn(uz, p[2]);
    float d = __fadd_rn(__fadd_rn(__fmul_rn(dx, dx), __fmul_rn(dy, dy)), __fmul_rn(dz, dz));
    if (d < d2v) {
      if (d < d1) {
        if (d < d0) { d2v = d1; i2 = i1; d1 = d0; i1 = i0; d0 = d; i0 = i; }
        else        { d2v = d1; i2 = i1; d1 = d;  i1 = i; }
      } else        { d2v = d;  i2 = i; }
    }
  }
#pragma unroll
  for (int m = 1; m <= 4; m <<= 1) {
    float e0 = __shfl_xor(d0, m), e1 = __shfl_xor(d1, m), e2 = __shfl_xor(d2v, m);
    int   f0 = __shfl_xor(i0, m), f1 = __shfl_xor(i1, m), f2 = __shfl_xor(i2, m);
    ins3(e0, f0, d0, i0, d1, i1, d2v, i2);
    ins3(e1, f1, d0, i0, d1, i1, d2v, i2);
    ins3(e2, f2, d0, i0, d1, i1, d2v, i2);
  }
  if (j == 0) {
    float w0 = 1.f / (d0 + 1e-8f), w1 = 1.f / (d1 + 1e-8f), w2 = 1.f / (d2v + 1e-8f);
    float s = w0 + w1 + w2;
    size_t base = ((size_t)b * N_ + n) * 3;
    idx[base] = i0; idx[base + 1] = i1; idx[base + 2] = i2;
    wgt[base] = w0 / s; wgt[base + 1] = w1 / s; wgt[base + 2] = w2 / s;
  }
}

// interp -> xt[b][n][256:768] bf16; 8 points/block, 32 lanes each, float4 gathers
__global__ __launch_bounds__(256) void k_interp(const float* __restrict__ kft, const int* __restrict__ idx,
                                                const float* __restrict__ wgt, unsigned short* __restrict__ xt) {
  int pb = blockIdx.x * 8 + (threadIdx.x >> 5);
  int lane = threadIdx.x & 31;
  int b = pb >> 13;
  size_t t3 = (size_t)pb * 3;
  int i0 = idx[t3], i1 = idx[t3 + 1], i2 = idx[t3 + 2];
  float w0 = wgt[t3], w1 = wgt[t3 + 1], w2 = wgt[t3 + 2];
  const f32x4* f0 = (const f32x4*)(kft + ((size_t)b * M_ + i0) * C2_);
  const f32x4* f1 = (const f32x4*)(kft + ((size_t)b * M_ + i1) * C2_);
  const f32x4* f2 = (const f32x4*)(kft + ((size_t)b * M_ + i2) * C2_);
  unsigned short* o = xt + (size_t)pb * CIN_ + C1_;
#pragma unroll
  for (int k = 0; k < 4; ++k) {
    int c4 = lane + 32 * k;
    f32x4 a = f0[c4], bb = f1[c4], cc = f2[c4];
    u16x4 r;
#pragma unroll
    for (int e = 0; e < 4; ++e) r[e] = f2bf(w0 * a[e] + w1 * bb[e] + w2 * cc[e]);
    *(u16x4*)(o + 4 * c4) = r;
  }
}

// ---------------- bf16 MFMA GEMM (m97 structure): C(256 x 8192) = A(256 x K) * X^T ----
// 128x128 tile, BK=64, 4 waves (2x2). Linear LDS [row][64 bf16] both operands.
// A (and B when !BN) staged via global_load_lds width=16 (linear dest, rule 21: no swizzle).
// BN=true: B reg-staged with fused scale/shift+ReLU (layer-1 BN applied on gemm2's input read).
// Fused epilogue: per-channel sum / sumsq atomics from the f32 accumulators.
// EPI 0: out point-major bf16 (ld=256).  EPI 1: out channel-major bf16 (ld=N_).

template <int K, int EPI, bool BN>
__global__ __launch_bounds__(256) void gemm_bt(const unsigned short* __restrict__ A,
                                               const unsigned short* __restrict__ Bm,
                                               unsigned short* __restrict__ C,
                                               float* __restrict__ sum, float* __restrict__ sq,
                                               const float* __restrict__ scale,
                                               const float* __restrict__ shift) {
  __shared__ __align__(16) char lds[32768];   // A: [0,16K), B: [16K,32K)
  __shared__ float lsc[256], lsh[256];
  const int tid = threadIdx.x;
  const int l = tid & 63;
  const int wv = tid >> 6;
  const int wr = wv >> 1, wc = wv & 1;
  const int b = blockIdx.z;
  const int o0 = blockIdx.y * 128;
  const int n0 = blockIdx.x * 128;
  const char* Ab = (const char*)A + (size_t)o0 * (K * 2);
  const char* Bb = (const char*)Bm + ((size_t)b * N_ + n0) * (K * 2);

  if (BN) { lsc[tid] = scale[tid]; lsh[tid] = shift[tid]; }   // covered by first loop barrier

  f32x4 zero = {0.f, 0.f, 0.f, 0.f};
  f32x4 acc[4][4];
#pragma unroll
  for (int i = 0; i < 4; ++i)
#pragma unroll
    for (int j = 0; j < 4; ++j) acc[i][j] = zero;

  // gload_lds geometry: wave wv stages rows [wv*32, wv*32+32), 4 instr x (8 rows = 1 KiB)
  const int grow = wv * 32 + (l >> 3);        // + i*8
  const int gcol = (l & 7) * 16;              // byte within 128-B k-row
  // reg-staging geometry (BN path): 4 chunks of 16B per thread
  int srow[4], scol[4];
#pragma unroll
  for (int i = 0; i < 4; ++i) { int q = tid + i * 256; srow[i] = q >> 3; scol[i] = (q & 7) * 16; }

  bf16x8 rb[4];
  if (BN) {
#pragma unroll
    for (int i = 0; i < 4; ++i)
      rb[i] = *(const bf16x8*)(Bb + (size_t)srow[i] * (K * 2) + scol[i]);
  }

  const int NK = K / 64;
  for (int kt = 0; kt < NK; ++kt) {
    __syncthreads();   // previous compute done -> safe to overwrite LDS
#pragma unroll
    for (int i = 0; i < 4; ++i) {
      int r = grow + i * 8;
      gload16(Ab + (size_t)r * (K * 2) + kt * 128 + gcol, lds + wv * 4096 + i * 1024);
      if (!BN)
        gload16(Bb + (size_t)r * (K * 2) + kt * 128 + gcol, lds + 16384 + wv * 4096 + i * 1024);
    }
    if (BN) {
#pragma unroll
      for (int i = 0; i < 4; ++i) {
        u16x8 v = *(u16x8*)&rb[i];
        u16x8 r;
        int c0 = kt * 64 + (scol[i] >> 1);
#pragma unroll
        for (int e = 0; e < 8; ++e) {
          float f = bf2f(v[e]) * lsc[c0 + e] + lsh[c0 + e];
          r[e] = f2bf(fmaxf(f, 0.f));
        }
        *(u16x8*)(lds + 16384 + srow[i] * 128 + scol[i]) = r;
      }
    }
    __syncthreads();   // drains vmcnt(0) + lgkm before LDS reads
    if (BN && kt + 1 < NK) {
      const char* Bk = Bb + (size_t)(kt + 1) * 128;
#pragma unroll
      for (int i = 0; i < 4; ++i)
        rb[i] = *(const bf16x8*)(Bk + (size_t)srow[i] * (K * 2) + scol[i]);
    }
#pragma unroll
    for (int kk = 0; kk < 2; ++kk) {
      bf16x8 af[4], bfr[4];
#pragma unroll
      for (int mi = 0; mi < 4; ++mi) {
        int row = wr * 64 + mi * 16 + (l & 15);
        af[mi] = *(const bf16x8*)(lds + row * 128 + kk * 64 + (l >> 4) * 16);
      }
#pragma unroll
      for (int ni = 0; ni < 4; ++ni) {
        int row = wc * 64 + ni * 16 + (l & 15);
        bfr[ni] = *(const bf16x8*)(lds + 16384 + row * 128 + kk * 64 + (l >> 4) * 16);
      }
#pragma unroll
      for (int mi = 0; mi < 4; ++mi)
#pragma unroll
        for (int ni = 0; ni < 4; ++ni)
          acc[mi][ni] = __builtin_amdgcn_mfma_f32_16x16x32_bf16(af[mi], bfr[ni], acc[mi][ni], 0, 0, 0);
    }
  }

  // C-write: frag mapping col(n)=lane&15, row(o)=(lane>>4)*4+r  [m89-verified]
#pragma unroll
  for (int mi = 0; mi < 4; ++mi) {
    int o = o0 + wr * 64 + mi * 16 + ((l >> 4) << 2);
#pragma unroll
    for (int ni = 0; ni < 4; ++ni) {
      int n = n0 + wc * 64 + ni * 16 + (l & 15);
      if (EPI == 0) {
        u16x4 pk;
#pragma unroll
        for (int r = 0; r < 4; ++r) pk[r] = f2bf(acc[mi][ni][r]);
        *(u16x4*)(C + ((size_t)b * N_ + n) * 256 + o) = pk;
      } else {
#pragma unroll
        for (int r = 0; r < 4; ++r)
          C[((size_t)b * 256 + (o + r)) * N_ + n] = f2bf(acc[mi][ni][r]);
      }
    }
  }

  // fused BN stats: reduce over n (ni frags + 16 lanes), atomicAdd per channel
#pragma unroll
  for (int mi = 0; mi < 4; ++mi) {
    float s[4] = {0.f, 0.f, 0.f, 0.f}, q[4] = {0.f, 0.f, 0.f, 0.f};
#pragma unroll
    for (int ni = 0; ni < 4; ++ni)
#pragma unroll
      for (int r = 0; r < 4; ++r) { float v = acc[mi][ni][r]; s[r] += v; q[r] = fmaf(v, v, q[r]); }
#pragma unroll
    for (int m = 1; m <= 8; m <<= 1)
#pragma unroll
      for (int r = 0; r < 4; ++r) { s[r] += __shfl_xor(s[r], m); q[r] += __shfl_xor(q[r], m); }
    if ((l & 15) == 0) {
      int o = o0 + wr * 64 + mi * 16 + ((l >> 4) << 2);
#pragma unroll
      for (int r = 0; r < 4; ++r) { atomicAdd(&sum[o + r], s[r]); atomicAdd(&sq[o + r], q[r]); }
    }
  }
}

// ---------------- BN finalize + output ----------------

__global__ void k_finalize(const float* __restrict__ sum, const float* __restrict__ sq,
                           const float* __restrict__ g, const float* __restrict__ bb,
                           float* __restrict__ scale, float* __restrict__ shift) {
  int c = threadIdx.x;
  const float inv_n = 1.f / 65536.f;
  float mean = sum[c] * inv_n;
  float var = sq[c] * inv_n - mean * mean;
  float rstd = rsqrtf(var + 1e-5f);
  float sc = g[c] * rstd;
  scale[c] = sc;
  shift[c] = bb[c] - mean * sc;
}

// BN+ReLU on channel-major bf16 -> fp32 d_out
__global__ void k_bnrelu_out(const unsigned short* __restrict__ y, const float* __restrict__ scale,
                             const float* __restrict__ shift, float* __restrict__ out) {
  size_t i = ((size_t)blockIdx.x * 256 + threadIdx.x) * 4;
  int c = (int)((i >> 13) & 255);
  float sc = scale[c], sh = shift[c];
  u16x4 v = *(const u16x4*)(y + i);
  f32x4 o;
#pragma unroll
  for (int k = 0; k < 4; ++k) o[k] = fmaxf(bf2f(v[k]) * sc + sh, 0.f);
  *(f32x4*)(out + i) = o;
}

// ---------------- launch ----------------

extern "C" void kernel_launch(void* const* d_in, const int* in_sizes, int n_in,
                              void* d_out, int out_size, void* d_ws, size_t ws_size,
                              hipStream_t stream) {
  const float* unknown = (const float*)d_in[0];
  const float* known   = (const float*)d_in[1];
  const float* uf      = (const float*)d_in[2];
  const float* kf      = (const float*)d_in[3];
  const float* W1      = (const float*)d_in[4];
  const float* g1      = (const float*)d_in[5];
  const float* b1      = (const float*)d_in[6];
  const float* W2      = (const float*)d_in[7];
  const float* g2      = (const float*)d_in[8];
  const float* b2      = (const float*)d_in[9];
  float* out = (float*)d_out;

  char* ws = (char*)d_ws;
  unsigned short* xt  = (unsigned short*)(ws);                    // (B,N,768) bf16   100,663,296 B
  unsigned short* y1  = (unsigned short*)(ws + 100663296);        // (B,N,256) bf16    33,554,432 B
  unsigned short* y2  = (unsigned short*)(ws + 134217728);        // (B,256,N) bf16    33,554,432 B
  float*          kft = (float*)(ws + 167772160);                 // (B,M,512) f32     16,777,216 B
  unsigned short* w1b = (unsigned short*)(ws + 184549376);        //                      393,216 B
  unsigned short* w2b = (unsigned short*)(ws + 184942592);        //                      131,072 B
  int*            idx = (int*)(ws + 185073664);                   //                      786,432 B
  float*          wgt = (float*)(ws + 185860096);                 //                      786,432 B
  float*          st  = (float*)(ws + 186646528);                 // stats block            8,192 B
  float *sum1 = st, *sq1 = st + 256, *sum2 = st + 512, *sq2 = st + 768;
  float *sc1 = st + 1024, *sh1 = st + 1280, *sc2 = st + 1536, *sh2 = st + 1792;

  k_zero<<<4, 256, 0, stream>>>(st, 1024);
  k_cast<<<768, 256, 0, stream>>>(W1, w1b, CMID_ * CIN_);
  k_cast<<<256, 256, 0, stream>>>(W2, w2b, COUT_ * CMID_);
  k_tr_kf<<<dim3(16, 32, B_), dim3(32, 8), 0, stream>>>(kf, kft);
  k_tr_uf<<<dim3(8, 256, B_), dim3(32, 8), 0, stream>>>(uf, xt);
  k_three_nn<<<B_ * 256, 256, 0, stream>>>(unknown, known, idx, wgt);
  k_interp<<<B_ * N_ / 8, 256, 0, stream>>>(kft, idx, wgt, xt);
  gemm_bt<CIN_, 0, false><<<dim3(64, 2, B_), 256, 0, stream>>>(w1b, xt, y1, sum1, sq1, nullptr, nullptr);
  k_finalize<<<1, 256, 0, stream>>>(sum1, sq1, g1, b1, sc1, sh1);
  gemm_bt<CMID_, 1, true><<<dim3(64, 2, B_), 256, 0, stream>>>(w2b, y1, y2, sum2, sq2, sc1, sh1);
  k_finalize<<<1, 256, 0, stream>>>(sum2, sq2, g2, b2, sc2, sh2);
  k_bnrelu_out<<<16384, 256, 0, stream>>>(y2, sc2, sh2, out);
}

// Round 4
// 375.254 us; speedup vs baseline: 1.0064x; 1.0064x over previous
//
#include <hip/hip_runtime.h>

#define B_    8
#define N_    8192
#define M_    1024
#define C1_   256
#define C2_   512
#define CIN_  768
#define CMID_ 256
#define COUT_ 256

typedef __attribute__((ext_vector_type(8))) __bf16 bf16x8;           // 4 VGPRs, MFMA A/B frag
typedef __attribute__((ext_vector_type(4))) float f32x4;             // MFMA C/D frag
typedef __attribute__((ext_vector_type(4))) unsigned short u16x4;
typedef __attribute__((ext_vector_type(8))) unsigned short u16x8;

__device__ __forceinline__ unsigned short f2bf(float f) {
  union { float f; unsigned u; } v; v.f = f;
  unsigned r = v.u + 0x7FFFu + ((v.u >> 16) & 1u);   // RNE
  return (unsigned short)(r >> 16);
}
__device__ __forceinline__ float bf2f(unsigned short h) {
  union { unsigned u; float f; } v; v.u = ((unsigned)h) << 16; return v.f;
}

// async global -> LDS, 16B per lane per wave-instruction (dest = uniform base + lane*16)
__device__ __forceinline__ void gload16(const void* g, void* l) {
  __builtin_amdgcn_global_load_lds((const __attribute__((address_space(1))) unsigned int*)g,
                                   (__attribute__((address_space(3))) unsigned int*)l, 16, 0, 0);
}

// ---------------- small utility kernels ----------------

__global__ void k_zero(float* p, int n) {
  int i = blockIdx.x * 256 + threadIdx.x;
  if (i < n) p[i] = 0.f;
}

__global__ void k_cast(const float* __restrict__ in, unsigned short* __restrict__ out, int n) {
  int i = blockIdx.x * 256 + threadIdx.x;
  if (i < n) out[i] = f2bf(in[i]);
}

// known_feats (B, C2, M) f32 -> kft (B, M, C2) f32
__global__ void k_tr_kf(const float* __restrict__ in, float* __restrict__ out) {
  __shared__ float t[32][33];
  int b = blockIdx.z;
  int c0 = blockIdx.x * 32, m0 = blockIdx.y * 32;
  int tx = threadIdx.x, ty = threadIdx.y;
  const float* ip = in + ((size_t)b * C2_ + c0) * M_ + m0;
#pragma unroll
  for (int i = 0; i < 32; i += 8) t[ty + i][tx] = ip[(size_t)(ty + i) * M_ + tx];
  __syncthreads();
  float* op = out + ((size_t)b * M_ + m0) * C2_ + c0;
#pragma unroll
  for (int i = 0; i < 32; i += 8) op[(size_t)(ty + i) * C2_ + tx] = t[tx][ty + i];
}

// unknow_feats (B, C1, N) f32 -> xt[b][n][0:256] bf16 (row stride CIN_)
__global__ void k_tr_uf(const float* __restrict__ in, unsigned short* __restrict__ out) {
  __shared__ float t[32][33];
  int b = blockIdx.z;
  int c0 = blockIdx.x * 32, n0 = blockIdx.y * 32;
  int tx = threadIdx.x, ty = threadIdx.y;
  const float* ip = in + ((size_t)b * C1_ + c0) * N_ + n0;
#pragma unroll
  for (int i = 0; i < 32; i += 8) t[ty + i][tx] = ip[(size_t)(ty + i) * N_ + tx];
  __syncthreads();
  unsigned short* op = out + ((size_t)b * N_ + n0) * CIN_ + c0;
#pragma unroll
  for (int i = 0; i < 32; i += 8) op[(size_t)(ty + i) * CIN_ + tx] = f2bf(t[tx][ty + i]);
}

// ---------------- three_nn: exact fp32 (d, idx)-lex semantics, 8 lanes/query ----------------

__device__ __forceinline__ void ins3(float db, int ib, float& d0, int& i0,
                                     float& d1, int& i1, float& d2, int& i2) {
  if (db < d2 || (db == d2 && ib < i2)) {
    if (db < d1 || (db == d1 && ib < i1)) {
      d2 = d1; i2 = i1;
      if (db < d0 || (db == d0 && ib < i0)) { d1 = d0; i1 = i0; d0 = db; i0 = ib; }
      else                                  { d1 = db; i1 = ib; }
    } else { d2 = db; i2 = ib; }
  }
}

__global__ __launch_bounds__(256) void k_three_nn(const float* __restrict__ unknown,
                                                  const float* __restrict__ known,
                                                  int* __restrict__ idx, float* __restrict__ wgt) {
  __shared__ __align__(16) float kpts[M_][4];
  int b = blockIdx.x >> 8;
  int n0 = (blockIdx.x & 255) << 5;
  for (int i = threadIdx.x; i < M_; i += 256) {
    const float* kp = known + ((size_t)b * M_ + i) * 3;
    kpts[i][0] = kp[0]; kpts[i][1] = kp[1]; kpts[i][2] = kp[2];
  }
  __syncthreads();
  const int l = threadIdx.x & 63;
  const int j = l & 7;
  const int q = ((threadIdx.x >> 6) << 3) + (l >> 3);
  const int n = n0 + q;
  const float* up = unknown + ((size_t)b * N_ + n) * 3;
  float ux = up[0], uy = up[1], uz = up[2];
  float d0 = 1e30f, d1 = 1e30f, d2v = 1e30f;
  int i0 = 0, i1 = 0, i2 = 0;
  for (int t = 0; t < 128; ++t) {
    int i = t * 8 + j;
    f32x4 p = *(const f32x4*)kpts[i];
    float dx = __fsub_rn(ux, p[0]);
    float dy = __fsub_rn(uy, p[1]);
    float dz = __fsub_rn(uz, p[2]);
    float d = __fadd_rn(__fadd_rn(__fmul_rn(dx, dx), __fmul_rn(dy, dy)), __fmul_rn(dz, dz));
    if (d < d2v) {
      if (d < d1) {
        if (d < d0) { d2v = d1; i2 = i1; d1 = d0; i1 = i0; d0 = d; i0 = i; }
        else        { d2v = d1; i2 = i1; d1 = d;  i1 = i; }
      } else        { d2v = d;  i2 = i; }
    }
  }
#pragma unroll
  for (int m = 1; m <= 4; m <<= 1) {
    float e0 = __shfl_xor(d0, m), e1 = __shfl_xor(d1, m), e2 = __shfl_xor(d2v, m);
    int   f0 = __shfl_xor(i0, m), f1 = __shfl_xor(i1, m), f2 = __shfl_xor(i2, m);
    ins3(e0, f0, d0, i0, d1, i1, d2v, i2);
    ins3(e1, f1, d0, i0, d1, i1, d2v, i2);
    ins3(e2, f2, d0, i0, d1, i1, d2v, i2);
  }
  if (j == 0) {
    float w0 = 1.f / (d0 + 1e-8f), w1 = 1.f / (d1 + 1e-8f), w2 = 1.f / (d2v + 1e-8f);
    float s = w0 + w1 + w2;
    size_t base = ((size_t)b * N_ + n) * 3;
    idx[base] = i0; idx[base + 1] = i1; idx[base + 2] = i2;
    wgt[base] = w0 / s; wgt[base + 1] = w1 / s; wgt[base + 2] = w2 / s;
  }
}

// interp -> xt[b][n][256:768] bf16; 8 points/block, 32 lanes each, float4 gathers
__global__ __launch_bounds__(256) void k_interp(const float* __restrict__ kft, const int* __restrict__ idx,
                                                const float* __restrict__ wgt, unsigned short* __restrict__ xt) {
  int pb = blockIdx.x * 8 + (threadIdx.x >> 5);
  int lane = threadIdx.x & 31;
  int b = pb >> 13;
  size_t t3 = (size_t)pb * 3;
  int i0 = idx[t3], i1 = idx[t3 + 1], i2 = idx[t3 + 2];
  float w0 = wgt[t3], w1 = wgt[t3 + 1], w2 = wgt[t3 + 2];
  const f32x4* f0 = (const f32x4*)(kft + ((size_t)b * M_ + i0) * C2_);
  const f32x4* f1 = (const f32x4*)(kft + ((size_t)b * M_ + i1) * C2_);
  const f32x4* f2 = (const f32x4*)(kft + ((size_t)b * M_ + i2) * C2_);
  unsigned short* o = xt + (size_t)pb * CIN_ + C1_;
#pragma unroll
  for (int k = 0; k < 4; ++k) {
    int c4 = lane + 32 * k;
    f32x4 a = f0[c4], bb = f1[c4], cc = f2[c4];
    u16x4 r;
#pragma unroll
    for (int e = 0; e < 4; ++e) r[e] = f2bf(w0 * a[e] + w1 * bb[e] + w2 * cc[e]);
    *(u16x4*)(o + 4 * c4) = r;
  }
}

// ---------------- bf16 MFMA GEMM (m97 structure + rule-21 swizzle): C = A * X^T ----
// 128x128 tile, BK=64, 4 waves (2x2). LDS logical layout [row][64 bf16] XOR-swizzled:
//   content at byte (row*128 + c) is global (row, c ^ ((row&7)<<4)).
// Staged via global_load_lds width=16 with LINEAR dest + pre-swizzled per-lane GLOBAL src
// (same involution; coalescing preserved: permutation stays within each 128-B segment).
// MFMA-phase ds_read_b128 applies the same XOR -> conflict-free (R2: 0 conflicts).
// BN=true: B reg-staged with fused scale/shift+ReLU, ds_write to swizzled addr.
// Fused epilogue: per-channel sum / sumsq atomics from the f32 accumulators.
// EPI 0: out point-major bf16 (ld=256).  EPI 1: out channel-major bf16 (ld=N_).

template <int K, int EPI, bool BN>
__global__ __launch_bounds__(256) void gemm_bt(const unsigned short* __restrict__ A,
                                               const unsigned short* __restrict__ Bm,
                                               unsigned short* __restrict__ C,
                                               float* __restrict__ sum, float* __restrict__ sq,
                                               const float* __restrict__ scale,
                                               const float* __restrict__ shift) {
  __shared__ __align__(16) char lds[32768];   // A: [0,16K), B: [16K,32K)
  __shared__ float lsc[256], lsh[256];
  const int tid = threadIdx.x;
  const int l = tid & 63;
  const int wv = tid >> 6;
  const int wr = wv >> 1, wc = wv & 1;
  const int b = blockIdx.z;
  const int o0 = blockIdx.y * 128;
  const int n0 = blockIdx.x * 128;
  const char* Ab = (const char*)A + (size_t)o0 * (K * 2);
  const char* Bb = (const char*)Bm + ((size_t)b * N_ + n0) * (K * 2);

  if (BN) { lsc[tid] = scale[tid]; lsh[tid] = shift[tid]; }   // covered by first loop barrier

  f32x4 zero = {0.f, 0.f, 0.f, 0.f};
  f32x4 acc[4][4];
#pragma unroll
  for (int i = 0; i < 4; ++i)
#pragma unroll
    for (int j = 0; j < 4; ++j) acc[i][j] = zero;

  // gload_lds geometry: wave wv stages rows [wv*32, wv*32+32), 4 instr x (8 rows = 1 KiB).
  // Linear LDS dest lane l -> (row = l>>3, colbyte = (l&7)*16). Pre-swizzled global col:
  const int grow = wv * 32 + (l >> 3);                  // + i*8
  const int gcol = (((l & 7) ^ (l >> 3)) * 16);         // (l&7)*16 XOR ((row&7)<<4)
  // reg-staging geometry (BN path): 4 chunks of 16B per thread
  int srow[4], scol[4];
#pragma unroll
  for (int i = 0; i < 4; ++i) { int q = tid + i * 256; srow[i] = q >> 3; scol[i] = (q & 7) * 16; }

  bf16x8 rb[4];
  if (BN) {
#pragma unroll
    for (int i = 0; i < 4; ++i)
      rb[i] = *(const bf16x8*)(Bb + (size_t)srow[i] * (K * 2) + scol[i]);
  }

  const int NK = K / 64;
  for (int kt = 0; kt < NK; ++kt) {
    __syncthreads();   // previous compute done -> safe to overwrite LDS
#pragma unroll
    for (int i = 0; i < 4; ++i) {
      int r = grow + i * 8;
      gload16(Ab + (size_t)r * (K * 2) + kt * 128 + gcol, lds + wv * 4096 + i * 1024);
      if (!BN)
        gload16(Bb + (size_t)r * (K * 2) + kt * 128 + gcol, lds + 16384 + wv * 4096 + i * 1024);
    }
    if (BN) {
#pragma unroll
      for (int i = 0; i < 4; ++i) {
        u16x8 v = *(u16x8*)&rb[i];
        u16x8 r;
        int c0 = kt * 64 + (scol[i] >> 1);
#pragma unroll
        for (int e = 0; e < 8; ++e) {
          float f = bf2f(v[e]) * lsc[c0 + e] + lsh[c0 + e];
          r[e] = f2bf(fmaxf(f, 0.f));
        }
        *(u16x8*)(lds + 16384 + srow[i] * 128 + (scol[i] ^ ((srow[i] & 7) << 4))) = r;
      }
    }
    __syncthreads();   // drains vmcnt(0) + lgkm before LDS reads
    if (BN && kt + 1 < NK) {
      const char* Bk = Bb + (size_t)(kt + 1) * 128;
#pragma unroll
      for (int i = 0; i < 4; ++i)
        rb[i] = *(const bf16x8*)(Bk + (size_t)srow[i] * (K * 2) + scol[i]);
    }
#pragma unroll
    for (int kk = 0; kk < 2; ++kk) {
      bf16x8 af[4], bfr[4];
#pragma unroll
      for (int mi = 0; mi < 4; ++mi) {
        int row = wr * 64 + mi * 16 + (l & 15);
        int cb = (kk * 64 + ((l >> 4) * 16)) ^ ((row & 7) << 4);
        af[mi] = *(const bf16x8*)(lds + row * 128 + cb);
      }
#pragma unroll
      for (int ni = 0; ni < 4; ++ni) {
        int row = wc * 64 + ni * 16 + (l & 15);
        int cb = (kk * 64 + ((l >> 4) * 16)) ^ ((row & 7) << 4);
        bfr[ni] = *(const bf16x8*)(lds + 16384 + row * 128 + cb);
      }
#pragma unroll
      for (int mi = 0; mi < 4; ++mi)
#pragma unroll
        for (int ni = 0; ni < 4; ++ni)
          acc[mi][ni] = __builtin_amdgcn_mfma_f32_16x16x32_bf16(af[mi], bfr[ni], acc[mi][ni], 0, 0, 0);
    }
  }

  // C-write: frag mapping col(n)=lane&15, row(o)=(lane>>4)*4+r  [m89-verified]
#pragma unroll
  for (int mi = 0; mi < 4; ++mi) {
    int o = o0 + wr * 64 + mi * 16 + ((l >> 4) << 2);
#pragma unroll
    for (int ni = 0; ni < 4; ++ni) {
      int n = n0 + wc * 64 + ni * 16 + (l & 15);
      if (EPI == 0) {
        u16x4 pk;
#pragma unroll
        for (int r = 0; r < 4; ++r) pk[r] = f2bf(acc[mi][ni][r]);
        *(u16x4*)(C + ((size_t)b * N_ + n) * 256 + o) = pk;
      } else {
#pragma unroll
        for (int r = 0; r < 4; ++r)
          C[((size_t)b * 256 + (o + r)) * N_ + n] = f2bf(acc[mi][ni][r]);
      }
    }
  }

  // fused BN stats: reduce over n (ni frags + 16 lanes), atomicAdd per channel
#pragma unroll
  for (int mi = 0; mi < 4; ++mi) {
    float s[4] = {0.f, 0.f, 0.f, 0.f}, q[4] = {0.f, 0.f, 0.f, 0.f};
#pragma unroll
    for (int ni = 0; ni < 4; ++ni)
#pragma unroll
      for (int r = 0; r < 4; ++r) { float v = acc[mi][ni][r]; s[r] += v; q[r] = fmaf(v, v, q[r]); }
#pragma unroll
    for (int m = 1; m <= 8; m <<= 1)
#pragma unroll
      for (int r = 0; r < 4; ++r) { s[r] += __shfl_xor(s[r], m); q[r] += __shfl_xor(q[r], m); }
    if ((l & 15) == 0) {
      int o = o0 + wr * 64 + mi * 16 + ((l >> 4) << 2);
#pragma unroll
      for (int r = 0; r < 4; ++r) { atomicAdd(&sum[o + r], s[r]); atomicAdd(&sq[o + r], q[r]); }
    }
  }
}

// ---------------- BN finalize + output ----------------

__global__ void k_finalize(const float* __restrict__ sum, const float* __restrict__ sq,
                           const float* __restrict__ g, const float* __restrict__ bb,
                           float* __restrict__ scale, float* __restrict__ shift) {
  int c = threadIdx.x;
  const float inv_n = 1.f / 65536.f;
  float mean = sum[c] * inv_n;
  float var = sq[c] * inv_n - mean * mean;
  float rstd = rsqrtf(var + 1e-5f);
  float sc = g[c] * rstd;
  scale[c] = sc;
  shift[c] = bb[c] - mean * sc;
}

// BN+ReLU on channel-major bf16 -> fp32 d_out
__global__ void k_bnrelu_out(const unsigned short* __restrict__ y, const float* __restrict__ scale,
                             const float* __restrict__ shift, float* __restrict__ out) {
  size_t i = ((size_t)blockIdx.x * 256 + threadIdx.x) * 4;
  int c = (int)((i >> 13) & 255);
  float sc = scale[c], sh = shift[c];
  u16x4 v = *(const u16x4*)(y + i);
  f32x4 o;
#pragma unroll
  for (int k = 0; k < 4; ++k) o[k] = fmaxf(bf2f(v[k]) * sc + sh, 0.f);
  *(f32x4*)(out + i) = o;
}

// ---------------- launch ----------------

extern "C" void kernel_launch(void* const* d_in, const int* in_sizes, int n_in,
                              void* d_out, int out_size, void* d_ws, size_t ws_size,
                              hipStream_t stream) {
  const float* unknown = (const float*)d_in[0];
  const float* known   = (const float*)d_in[1];
  const float* uf      = (const float*)d_in[2];
  const float* kf      = (const float*)d_in[3];
  const float* W1      = (const float*)d_in[4];
  const float* g1      = (const float*)d_in[5];
  const float* b1      = (const float*)d_in[6];
  const float* W2      = (const float*)d_in[7];
  const float* g2      = (const float*)d_in[8];
  const float* b2      = (const float*)d_in[9];
  float* out = (float*)d_out;

  char* ws = (char*)d_ws;
  unsigned short* xt  = (unsigned short*)(ws);                    // (B,N,768) bf16   100,663,296 B
  unsigned short* y1  = (unsigned short*)(ws + 100663296);        // (B,N,256) bf16    33,554,432 B
  unsigned short* y2  = (unsigned short*)(ws + 134217728);        // (B,256,N) bf16    33,554,432 B
  float*          kft = (float*)(ws + 167772160);                 // (B,M,512) f32     16,777,216 B
  unsigned short* w1b = (unsigned short*)(ws + 184549376);        //                      393,216 B
  unsigned short* w2b = (unsigned short*)(ws + 184942592);        //                      131,072 B
  int*            idx = (int*)(ws + 185073664);                   //                      786,432 B
  float*          wgt = (float*)(ws + 185860096);                 //                      786,432 B
  float*          st  = (float*)(ws + 186646528);                 // stats block            8,192 B
  float *sum1 = st, *sq1 = st + 256, *sum2 = st + 512, *sq2 = st + 768;
  float *sc1 = st + 1024, *sh1 = st + 1280, *sc2 = st + 1536, *sh2 = st + 1792;

  k_zero<<<4, 256, 0, stream>>>(st, 1024);
  k_cast<<<768, 256, 0, stream>>>(W1, w1b, CMID_ * CIN_);
  k_cast<<<256, 256, 0, stream>>>(W2, w2b, COUT_ * CMID_);
  k_tr_kf<<<dim3(16, 32, B_), dim3(32, 8), 0, stream>>>(kf, kft);
  k_tr_uf<<<dim3(8, 256, B_), dim3(32, 8), 0, stream>>>(uf, xt);
  k_three_nn<<<B_ * 256, 256, 0, stream>>>(unknown, known, idx, wgt);
  k_interp<<<B_ * N_ / 8, 256, 0, stream>>>(kft, idx, wgt, xt);
  gemm_bt<CIN_, 0, false><<<dim3(64, 2, B_), 256, 0, stream>>>(w1b, xt, y1, sum1, sq1, nullptr, nullptr);
  k_finalize<<<1, 256, 0, stream>>>(sum1, sq1, g1, b1, sc1, sh1);
  gemm_bt<CMID_, 1, true><<<dim3(64, 2, B_), 256, 0, stream>>>(w2b, y1, y2, sum2, sq2, sc1, sh1);
  k_finalize<<<1, 256, 0, stream>>>(sum2, sq2, g2, b2, sc2, sh2);
  k_bnrelu_out<<<16384, 256, 0, stream>>>(y2, sc2, sh2, out);
}

// Round 5
// 205.973 us; speedup vs baseline: 1.8335x; 1.8219x over previous
//
#include <hip/hip_runtime.h>

#define B_    8
#define N_    8192
#define M_    1024
#define C1_   256
#define C2_   512
#define CIN_  768
#define CMID_ 256
#define COUT_ 256

typedef __attribute__((ext_vector_type(8))) __bf16 bf16x8;           // 4 VGPRs, MFMA A/B frag
typedef __attribute__((ext_vector_type(4))) float f32x4;             // MFMA C/D frag
typedef __attribute__((ext_vector_type(4))) unsigned short u16x4;
typedef __attribute__((ext_vector_type(8))) unsigned short u16x8;

__device__ __forceinline__ unsigned short f2bf(float f) {
  union { float f; unsigned u; } v; v.f = f;
  unsigned r = v.u + 0x7FFFu + ((v.u >> 16) & 1u);   // RNE
  return (unsigned short)(r >> 16);
}
__device__ __forceinline__ float bf2f(unsigned short h) {
  union { unsigned u; float f; } v; v.u = ((unsigned)h) << 16; return v.f;
}

// async global -> LDS, 16B per lane per wave-instruction (dest = uniform base + lane*16)
__device__ __forceinline__ void gload16(const void* g, void* l) {
  __builtin_amdgcn_global_load_lds((const __attribute__((address_space(1))) unsigned int*)g,
                                   (__attribute__((address_space(3))) unsigned int*)l, 16, 0, 0);
}

// ---------------- small utility kernels ----------------

__global__ void k_cast(const float* __restrict__ in, unsigned short* __restrict__ out, int n) {
  int i = blockIdx.x * 256 + threadIdx.x;
  if (i < n) out[i] = f2bf(in[i]);
}

// known_feats (B, C2, M) f32 -> kft (B, M, C2) f32
__global__ void k_tr_kf(const float* __restrict__ in, float* __restrict__ out) {
  __shared__ float t[32][33];
  int b = blockIdx.z;
  int c0 = blockIdx.x * 32, m0 = blockIdx.y * 32;
  int tx = threadIdx.x, ty = threadIdx.y;
  const float* ip = in + ((size_t)b * C2_ + c0) * M_ + m0;
#pragma unroll
  for (int i = 0; i < 32; i += 8) t[ty + i][tx] = ip[(size_t)(ty + i) * M_ + tx];
  __syncthreads();
  float* op = out + ((size_t)b * M_ + m0) * C2_ + c0;
#pragma unroll
  for (int i = 0; i < 32; i += 8) op[(size_t)(ty + i) * C2_ + tx] = t[tx][ty + i];
}

// unknow_feats (B, C1, N) f32 -> xt[b][n][0:256] bf16 (row stride CIN_)
__global__ void k_tr_uf(const float* __restrict__ in, unsigned short* __restrict__ out) {
  __shared__ float t[32][33];
  int b = blockIdx.z;
  int c0 = blockIdx.x * 32, n0 = blockIdx.y * 32;
  int tx = threadIdx.x, ty = threadIdx.y;
  const float* ip = in + ((size_t)b * C1_ + c0) * N_ + n0;
#pragma unroll
  for (int i = 0; i < 32; i += 8) t[ty + i][tx] = ip[(size_t)(ty + i) * N_ + tx];
  __syncthreads();
  unsigned short* op = out + ((size_t)b * N_ + n0) * CIN_ + c0;
#pragma unroll
  for (int i = 0; i < 32; i += 8) op[(size_t)(ty + i) * CIN_ + tx] = f2bf(t[tx][ty + i]);
}

// ---------------- three_nn: exact fp32 (d, idx)-lex semantics, 8 lanes/query ----------------

__device__ __forceinline__ void ins3(float db, int ib, float& d0, int& i0,
                                     float& d1, int& i1, float& d2, int& i2) {
  if (db < d2 || (db == d2 && ib < i2)) {
    if (db < d1 || (db == d1 && ib < i1)) {
      d2 = d1; i2 = i1;
      if (db < d0 || (db == d0 && ib < i0)) { d1 = d0; i1 = i0; d0 = db; i0 = ib; }
      else                                  { d1 = db; i1 = ib; }
    } else { d2 = db; i2 = ib; }
  }
}

__global__ __launch_bounds__(256) void k_three_nn(const float* __restrict__ unknown,
                                                  const float* __restrict__ known,
                                                  int* __restrict__ idx, float* __restrict__ wgt) {
  __shared__ __align__(16) float kpts[M_][4];
  int b = blockIdx.x >> 8;
  int n0 = (blockIdx.x & 255) << 5;
  for (int i = threadIdx.x; i < M_; i += 256) {
    const float* kp = known + ((size_t)b * M_ + i) * 3;
    kpts[i][0] = kp[0]; kpts[i][1] = kp[1]; kpts[i][2] = kp[2];
  }
  __syncthreads();
  const int l = threadIdx.x & 63;
  const int j = l & 7;
  const int q = ((threadIdx.x >> 6) << 3) + (l >> 3);
  const int n = n0 + q;
  const float* up = unknown + ((size_t)b * N_ + n) * 3;
  float ux = up[0], uy = up[1], uz = up[2];
  float d0 = 1e30f, d1 = 1e30f, d2v = 1e30f;
  int i0 = 0, i1 = 0, i2 = 0;
  for (int t = 0; t < 128; ++t) {
    int i = t * 8 + j;
    f32x4 p = *(const f32x4*)kpts[i];
    float dx = __fsub_rn(ux, p[0]);
    float dy = __fsub_rn(uy, p[1]);
    float dz = __fsub_rn(uz, p[2]);
    float d = __fadd_rn(__fadd_rn(__fmul_rn(dx, dx), __fmul_rn(dy, dy)), __fmul_rn(dz, dz));
    if (d < d2v) {
      if (d < d1) {
        if (d < d0) { d2v = d1; i2 = i1; d1 = d0; i1 = i0; d0 = d; i0 = i; }
        else        { d2v = d1; i2 = i1; d1 = d;  i1 = i; }
      } else        { d2v = d;  i2 = i; }
    }
  }
#pragma unroll
  for (int m = 1; m <= 4; m <<= 1) {
    float e0 = __shfl_xor(d0, m), e1 = __shfl_xor(d1, m), e2 = __shfl_xor(d2v, m);
    int   f0 = __shfl_xor(i0, m), f1 = __shfl_xor(i1, m), f2 = __shfl_xor(i2, m);
    ins3(e0, f0, d0, i0, d1, i1, d2v, i2);
    ins3(e1, f1, d0, i0, d1, i1, d2v, i2);
    ins3(e2, f2, d0, i0, d1, i1, d2v, i2);
  }
  if (j == 0) {
    float w0 = 1.f / (d0 + 1e-8f), w1 = 1.f / (d1 + 1e-8f), w2 = 1.f / (d2v + 1e-8f);
    float s = w0 + w1 + w2;
    size_t base = ((size_t)b * N_ + n) * 3;
    idx[base] = i0; idx[base + 1] = i1; idx[base + 2] = i2;
    wgt[base] = w0 / s; wgt[base + 1] = w1 / s; wgt[base + 2] = w2 / s;
  }
}

// interp -> xt[b][n][256:768] bf16; 8 points/block, 32 lanes each, float4 gathers
__global__ __launch_bounds__(256) void k_interp(const float* __restrict__ kft, const int* __restrict__ idx,
                                                const float* __restrict__ wgt, unsigned short* __restrict__ xt) {
  int pb = blockIdx.x * 8 + (threadIdx.x >> 5);
  int lane = threadIdx.x & 31;
  int b = pb >> 13;
  size_t t3 = (size_t)pb * 3;
  int i0 = idx[t3], i1 = idx[t3 + 1], i2 = idx[t3 + 2];
  float w0 = wgt[t3], w1 = wgt[t3 + 1], w2 = wgt[t3 + 2];
  const f32x4* f0 = (const f32x4*)(kft + ((size_t)b * M_ + i0) * C2_);
  const f32x4* f1 = (const f32x4*)(kft + ((size_t)b * M_ + i1) * C2_);
  const f32x4* f2 = (const f32x4*)(kft + ((size_t)b * M_ + i2) * C2_);
  unsigned short* o = xt + (size_t)pb * CIN_ + C1_;
#pragma unroll
  for (int k = 0; k < 4; ++k) {
    int c4 = lane + 32 * k;
    f32x4 a = f0[c4], bb = f1[c4], cc = f2[c4];
    u16x4 r;
#pragma unroll
    for (int e = 0; e < 4; ++e) r[e] = f2bf(w0 * a[e] + w1 * bb[e] + w2 * cc[e]);
    *(u16x4*)(o + 4 * c4) = r;
  }
}

// ---------------- bf16 MFMA GEMM (m97 structure + rule-21 swizzle): C = A * X^T ----
// 128x128 tile, BK=64, 4 waves (2x2). LDS logical layout [row][64 bf16] XOR-swizzled:
//   content at byte (row*128 + c) is global (row, c ^ ((row&7)<<4)).
// Staged via global_load_lds width=16 with LINEAR dest + pre-swizzled per-lane GLOBAL src.
// MFMA-phase ds_read_b128 applies the same XOR -> conflict-free (R2: 0 conflicts).
// BN=true: B reg-staged with fused scale/shift+ReLU, ds_write to swizzled addr.
// Stats epilogue: per-block PARTIAL sums to unique scratch slots — NO atomics.
// (R3/R4 lesson: 524K same-address atomicAdds serialized ~150 us per gemm dispatch.)
// EPI 0: out point-major bf16 (ld=256).  EPI 1: out channel-major bf16 (ld=N_).

template <int K, int EPI, bool BN>
__global__ __launch_bounds__(256) void gemm_bt(const unsigned short* __restrict__ A,
                                               const unsigned short* __restrict__ Bm,
                                               unsigned short* __restrict__ C,
                                               float* __restrict__ psum, float* __restrict__ psq,
                                               const float* __restrict__ scale,
                                               const float* __restrict__ shift) {
  __shared__ __align__(16) char lds[32768];   // A: [0,16K), B: [16K,32K)
  __shared__ float lsc[256], lsh[256];
  const int tid = threadIdx.x;
  const int l = tid & 63;
  const int wv = tid >> 6;
  const int wr = wv >> 1, wc = wv & 1;
  const int b = blockIdx.z;
  const int o0 = blockIdx.y * 128;
  const int n0 = blockIdx.x * 128;
  const char* Ab = (const char*)A + (size_t)o0 * (K * 2);
  const char* Bb = (const char*)Bm + ((size_t)b * N_ + n0) * (K * 2);

  if (BN) { lsc[tid] = scale[tid]; lsh[tid] = shift[tid]; }   // covered by first loop barrier

  f32x4 zero = {0.f, 0.f, 0.f, 0.f};
  f32x4 acc[4][4];
#pragma unroll
  for (int i = 0; i < 4; ++i)
#pragma unroll
    for (int j = 0; j < 4; ++j) acc[i][j] = zero;

  // gload_lds geometry: wave wv stages rows [wv*32, wv*32+32), 4 instr x (8 rows = 1 KiB).
  // Linear LDS dest lane l -> (row = l>>3, colbyte = (l&7)*16). Pre-swizzled global col:
  const int grow = wv * 32 + (l >> 3);                  // + i*8
  const int gcol = (((l & 7) ^ (l >> 3)) * 16);         // (l&7)*16 XOR ((row&7)<<4)
  // reg-staging geometry (BN path): 4 chunks of 16B per thread
  int srow[4], scol[4];
#pragma unroll
  for (int i = 0; i < 4; ++i) { int q = tid + i * 256; srow[i] = q >> 3; scol[i] = (q & 7) * 16; }

  bf16x8 rb[4];
  if (BN) {
#pragma unroll
    for (int i = 0; i < 4; ++i)
      rb[i] = *(const bf16x8*)(Bb + (size_t)srow[i] * (K * 2) + scol[i]);
  }

  const int NK = K / 64;
  for (int kt = 0; kt < NK; ++kt) {
    __syncthreads();   // previous compute done -> safe to overwrite LDS
#pragma unroll
    for (int i = 0; i < 4; ++i) {
      int r = grow + i * 8;
      gload16(Ab + (size_t)r * (K * 2) + kt * 128 + gcol, lds + wv * 4096 + i * 1024);
      if (!BN)
        gload16(Bb + (size_t)r * (K * 2) + kt * 128 + gcol, lds + 16384 + wv * 4096 + i * 1024);
    }
    if (BN) {
#pragma unroll
      for (int i = 0; i < 4; ++i) {
        u16x8 v = *(u16x8*)&rb[i];
        u16x8 r;
        int c0 = kt * 64 + (scol[i] >> 1);
#pragma unroll
        for (int e = 0; e < 8; ++e) {
          float f = bf2f(v[e]) * lsc[c0 + e] + lsh[c0 + e];
          r[e] = f2bf(fmaxf(f, 0.f));
        }
        *(u16x8*)(lds + 16384 + srow[i] * 128 + (scol[i] ^ ((srow[i] & 7) << 4))) = r;
      }
    }
    __syncthreads();   // drains vmcnt(0) + lgkm before LDS reads
    if (BN && kt + 1 < NK) {
      const char* Bk = Bb + (size_t)(kt + 1) * 128;
#pragma unroll
      for (int i = 0; i < 4; ++i)
        rb[i] = *(const bf16x8*)(Bk + (size_t)srow[i] * (K * 2) + scol[i]);
    }
#pragma unroll
    for (int kk = 0; kk < 2; ++kk) {
      bf16x8 af[4], bfr[4];
#pragma unroll
      for (int mi = 0; mi < 4; ++mi) {
        int row = wr * 64 + mi * 16 + (l & 15);
        int cb = (kk * 64 + ((l >> 4) * 16)) ^ ((row & 7) << 4);
        af[mi] = *(const bf16x8*)(lds + row * 128 + cb);
      }
#pragma unroll
      for (int ni = 0; ni < 4; ++ni) {
        int row = wc * 64 + ni * 16 + (l & 15);
        int cb = (kk * 64 + ((l >> 4) * 16)) ^ ((row & 7) << 4);
        bfr[ni] = *(const bf16x8*)(lds + 16384 + row * 128 + cb);
      }
#pragma unroll
      for (int mi = 0; mi < 4; ++mi)
#pragma unroll
        for (int ni = 0; ni < 4; ++ni)
          acc[mi][ni] = __builtin_amdgcn_mfma_f32_16x16x32_bf16(af[mi], bfr[ni], acc[mi][ni], 0, 0, 0);
    }
  }

  // C-write: frag mapping col(n)=lane&15, row(o)=(lane>>4)*4+r  [m89-verified]
#pragma unroll
  for (int mi = 0; mi < 4; ++mi) {
    int o = o0 + wr * 64 + mi * 16 + ((l >> 4) << 2);
#pragma unroll
    for (int ni = 0; ni < 4; ++ni) {
      int n = n0 + wc * 64 + ni * 16 + (l & 15);
      if (EPI == 0) {
        u16x4 pk;
#pragma unroll
        for (int r = 0; r < 4; ++r) pk[r] = f2bf(acc[mi][ni][r]);
        *(u16x4*)(C + ((size_t)b * N_ + n) * 256 + o) = pk;
      } else {
#pragma unroll
        for (int r = 0; r < 4; ++r)
          C[((size_t)b * 256 + (o + r)) * N_ + n] = f2bf(acc[mi][ni][r]);
      }
    }
  }

  // partial BN stats: reduce over n within wave, write to a unique slot (no contention)
  const int slot = (blockIdx.z * 64 + blockIdx.x) * 2 + wc;   // [0, 1024)
#pragma unroll
  for (int mi = 0; mi < 4; ++mi) {
    float s[4] = {0.f, 0.f, 0.f, 0.f}, q[4] = {0.f, 0.f, 0.f, 0.f};
#pragma unroll
    for (int ni = 0; ni < 4; ++ni)
#pragma unroll
      for (int r = 0; r < 4; ++r) { float v = acc[mi][ni][r]; s[r] += v; q[r] = fmaf(v, v, q[r]); }
#pragma unroll
    for (int m = 1; m <= 8; m <<= 1)
#pragma unroll
      for (int r = 0; r < 4; ++r) { s[r] += __shfl_xor(s[r], m); q[r] += __shfl_xor(q[r], m); }
    if ((l & 15) == 0) {
      int o = o0 + wr * 64 + mi * 16 + ((l >> 4) << 2);
#pragma unroll
      for (int r = 0; r < 4; ++r) {
        psum[(size_t)(o + r) * 1024 + slot] = s[r];
        psq [(size_t)(o + r) * 1024 + slot] = q[r];
      }
    }
  }
}

// ---------------- BN finalize: reduce 1024 partials per channel, compute scale/shift ----------------

__global__ __launch_bounds__(256) void k_finalize(const float* __restrict__ psum,
                                                  const float* __restrict__ psq,
                                                  const float* __restrict__ g,
                                                  const float* __restrict__ bb,
                                                  float* __restrict__ scale,
                                                  float* __restrict__ shift) {
  int c = blockIdx.x;
  const float* ps = psum + (size_t)c * 1024;
  const float* pq = psq + (size_t)c * 1024;
  float s = 0.f, q = 0.f;
#pragma unroll
  for (int k = 0; k < 4; ++k) { s += ps[threadIdx.x + 256 * k]; q += pq[threadIdx.x + 256 * k]; }
#pragma unroll
  for (int off = 32; off; off >>= 1) { s += __shfl_down(s, off); q += __shfl_down(q, off); }
  __shared__ float rs[4], rq[4];
  if ((threadIdx.x & 63) == 0) { rs[threadIdx.x >> 6] = s; rq[threadIdx.x >> 6] = q; }
  __syncthreads();
  if (threadIdx.x == 0) {
    float S = rs[0] + rs[1] + rs[2] + rs[3];
    float Q = rq[0] + rq[1] + rq[2] + rq[3];
    const float inv_n = 1.f / 65536.f;
    float mean = S * inv_n;
    float var = Q * inv_n - mean * mean;
    float rstd = rsqrtf(var + 1e-5f);
    float sc = g[c] * rstd;
    scale[c] = sc;
    shift[c] = bb[c] - mean * sc;
  }
}

// BN+ReLU on channel-major bf16 -> fp32 d_out
__global__ void k_bnrelu_out(const unsigned short* __restrict__ y, const float* __restrict__ scale,
                             const float* __restrict__ shift, float* __restrict__ out) {
  size_t i = ((size_t)blockIdx.x * 256 + threadIdx.x) * 4;
  int c = (int)((i >> 13) & 255);
  float sc = scale[c], sh = shift[c];
  u16x4 v = *(const u16x4*)(y + i);
  f32x4 o;
#pragma unroll
  for (int k = 0; k < 4; ++k) o[k] = fmaxf(bf2f(v[k]) * sc + sh, 0.f);
  *(f32x4*)(out + i) = o;
}

// ---------------- launch ----------------

extern "C" void kernel_launch(void* const* d_in, const int* in_sizes, int n_in,
                              void* d_out, int out_size, void* d_ws, size_t ws_size,
                              hipStream_t stream) {
  const float* unknown = (const float*)d_in[0];
  const float* known   = (const float*)d_in[1];
  const float* uf      = (const float*)d_in[2];
  const float* kf      = (const float*)d_in[3];
  const float* W1      = (const float*)d_in[4];
  const float* g1      = (const float*)d_in[5];
  const float* b1      = (const float*)d_in[6];
  const float* W2      = (const float*)d_in[7];
  const float* g2      = (const float*)d_in[8];
  const float* b2      = (const float*)d_in[9];
  float* out = (float*)d_out;

  char* ws = (char*)d_ws;
  unsigned short* xt  = (unsigned short*)(ws);                    // (B,N,768) bf16   100,663,296 B
  unsigned short* y1  = (unsigned short*)(ws + 100663296);        // (B,N,256) bf16    33,554,432 B
  unsigned short* y2  = (unsigned short*)(ws + 134217728);        // (B,256,N) bf16    33,554,432 B
  float*          kft = (float*)(ws + 167772160);                 // (B,M,512) f32     16,777,216 B
  // psum/psq alias kft's region: kft is dead after k_interp; both gemms reuse sequentially
  float*          psum = (float*)(ws + 167772160);                // 256*1024 f32       1,048,576 B
  float*          psq  = (float*)(ws + 168820736);                // 256*1024 f32       1,048,576 B
  unsigned short* w1b = (unsigned short*)(ws + 184549376);        //                      393,216 B
  unsigned short* w2b = (unsigned short*)(ws + 184942592);        //                      131,072 B
  int*            idx = (int*)(ws + 185073664);                   //                      786,432 B
  float*          wgt = (float*)(ws + 185860096);                 //                      786,432 B
  float*          st  = (float*)(ws + 186646528);                 // sc/sh block            4,096 B
  float *sc1 = st, *sh1 = st + 256, *sc2 = st + 512, *sh2 = st + 768;

  k_cast<<<768, 256, 0, stream>>>(W1, w1b, CMID_ * CIN_);
  k_cast<<<256, 256, 0, stream>>>(W2, w2b, COUT_ * CMID_);
  k_tr_kf<<<dim3(16, 32, B_), dim3(32, 8), 0, stream>>>(kf, kft);
  k_tr_uf<<<dim3(8, 256, B_), dim3(32, 8), 0, stream>>>(uf, xt);
  k_three_nn<<<B_ * 256, 256, 0, stream>>>(unknown, known, idx, wgt);
  k_interp<<<B_ * N_ / 8, 256, 0, stream>>>(kft, idx, wgt, xt);
  gemm_bt<CIN_, 0, false><<<dim3(64, 2, B_), 256, 0, stream>>>(w1b, xt, y1, psum, psq, nullptr, nullptr);
  k_finalize<<<256, 256, 0, stream>>>(psum, psq, g1, b1, sc1, sh1);
  gemm_bt<CMID_, 1, true><<<dim3(64, 2, B_), 256, 0, stream>>>(w2b, y1, y2, psum, psq, sc1, sh1);
  k_finalize<<<256, 256, 0, stream>>>(psum, psq, g2, b2, sc2, sh2);
  k_bnrelu_out<<<16384, 256, 0, stream>>>(y2, sc2, sh2, out);
}

// Round 6
// 197.152 us; speedup vs baseline: 1.9156x; 1.0447x over previous
//
#include <hip/hip_runtime.h>

#define B_    8
#define N_    8192
#define M_    1024
#define C1_   256
#define C2_   512
#define CIN_  768
#define CMID_ 256
#define COUT_ 256

typedef __attribute__((ext_vector_type(8))) __bf16 bf16x8;           // 4 VGPRs, MFMA A/B frag
typedef __attribute__((ext_vector_type(4))) float f32x4;             // MFMA C/D frag
typedef __attribute__((ext_vector_type(4))) unsigned short u16x4;
typedef __attribute__((ext_vector_type(8))) unsigned short u16x8;

__device__ __forceinline__ unsigned short f2bf(float f) {
  union { float f; unsigned u; } v; v.f = f;
  unsigned r = v.u + 0x7FFFu + ((v.u >> 16) & 1u);   // RNE
  return (unsigned short)(r >> 16);
}
__device__ __forceinline__ float bf2f(unsigned short h) {
  union { unsigned u; float f; } v; v.u = ((unsigned)h) << 16; return v.f;
}

// async global -> LDS, 16B per lane per wave-instruction (dest = uniform base + lane*16)
__device__ __forceinline__ void gload16(const void* g, void* l) {
  __builtin_amdgcn_global_load_lds((const __attribute__((address_space(1))) unsigned int*)g,
                                   (__attribute__((address_space(3))) unsigned int*)l, 16, 0, 0);
}

// ---------------- small utility kernels ----------------

__global__ void k_cast(const float* __restrict__ in, unsigned short* __restrict__ out, int n) {
  int i = blockIdx.x * 256 + threadIdx.x;
  if (i < n) out[i] = f2bf(in[i]);
}

// known_feats (B, C2, M) f32 -> kft (B, M, C2) f32
__global__ void k_tr_kf(const float* __restrict__ in, float* __restrict__ out) {
  __shared__ float t[32][33];
  int b = blockIdx.z;
  int c0 = blockIdx.x * 32, m0 = blockIdx.y * 32;
  int tx = threadIdx.x, ty = threadIdx.y;
  const float* ip = in + ((size_t)b * C2_ + c0) * M_ + m0;
#pragma unroll
  for (int i = 0; i < 32; i += 8) t[ty + i][tx] = ip[(size_t)(ty + i) * M_ + tx];
  __syncthreads();
  float* op = out + ((size_t)b * M_ + m0) * C2_ + c0;
#pragma unroll
  for (int i = 0; i < 32; i += 8) op[(size_t)(ty + i) * C2_ + tx] = t[tx][ty + i];
}

// unknow_feats (B, C1, N) f32 -> xt[b][n][0:256] bf16 (row stride CIN_)
__global__ void k_tr_uf(const float* __restrict__ in, unsigned short* __restrict__ out) {
  __shared__ float t[32][33];
  int b = blockIdx.z;
  int c0 = blockIdx.x * 32, n0 = blockIdx.y * 32;
  int tx = threadIdx.x, ty = threadIdx.y;
  const float* ip = in + ((size_t)b * C1_ + c0) * N_ + n0;
#pragma unroll
  for (int i = 0; i < 32; i += 8) t[ty + i][tx] = ip[(size_t)(ty + i) * N_ + tx];
  __syncthreads();
  unsigned short* op = out + ((size_t)b * N_ + n0) * CIN_ + c0;
#pragma unroll
  for (int i = 0; i < 32; i += 8) op[(size_t)(ty + i) * CIN_ + tx] = f2bf(t[tx][ty + i]);
}

// ---------------- three_nn: exact fp32 (d, idx)-lex semantics, 8 lanes/query ----------------

__device__ __forceinline__ void ins3(float db, int ib, float& d0, int& i0,
                                     float& d1, int& i1, float& d2, int& i2) {
  if (db < d2 || (db == d2 && ib < i2)) {
    if (db < d1 || (db == d1 && ib < i1)) {
      d2 = d1; i2 = i1;
      if (db < d0 || (db == d0 && ib < i0)) { d1 = d0; i1 = i0; d0 = db; i0 = ib; }
      else                                  { d1 = db; i1 = ib; }
    } else { d2 = db; i2 = ib; }
  }
}

__global__ __launch_bounds__(256) void k_three_nn(const float* __restrict__ unknown,
                                                  const float* __restrict__ known,
                                                  int* __restrict__ idx, float* __restrict__ wgt) {
  __shared__ __align__(16) float kpts[M_][4];
  int b = blockIdx.x >> 8;
  int n0 = (blockIdx.x & 255) << 5;
  for (int i = threadIdx.x; i < M_; i += 256) {
    const float* kp = known + ((size_t)b * M_ + i) * 3;
    kpts[i][0] = kp[0]; kpts[i][1] = kp[1]; kpts[i][2] = kp[2];
  }
  __syncthreads();
  const int l = threadIdx.x & 63;
  const int j = l & 7;
  const int q = ((threadIdx.x >> 6) << 3) + (l >> 3);
  const int n = n0 + q;
  const float* up = unknown + ((size_t)b * N_ + n) * 3;
  float ux = up[0], uy = up[1], uz = up[2];
  float d0 = 1e30f, d1 = 1e30f, d2v = 1e30f;
  int i0 = 0, i1 = 0, i2 = 0;
  for (int t = 0; t < 128; ++t) {
    int i = t * 8 + j;
    f32x4 p = *(const f32x4*)kpts[i];
    float dx = __fsub_rn(ux, p[0]);
    float dy = __fsub_rn(uy, p[1]);
    float dz = __fsub_rn(uz, p[2]);
    float d = __fadd_rn(__fadd_rn(__fmul_rn(dx, dx), __fmul_rn(dy, dy)), __fmul_rn(dz, dz));
    if (d < d2v) {
      if (d < d1) {
        if (d < d0) { d2v = d1; i2 = i1; d1 = d0; i1 = i0; d0 = d; i0 = i; }
        else        { d2v = d1; i2 = i1; d1 = d;  i1 = i; }
      } else        { d2v = d;  i2 = i; }
    }
  }
#pragma unroll
  for (int m = 1; m <= 4; m <<= 1) {
    float e0 = __shfl_xor(d0, m), e1 = __shfl_xor(d1, m), e2 = __shfl_xor(d2v, m);
    int   f0 = __shfl_xor(i0, m), f1 = __shfl_xor(i1, m), f2 = __shfl_xor(i2, m);
    ins3(e0, f0, d0, i0, d1, i1, d2v, i2);
    ins3(e1, f1, d0, i0, d1, i1, d2v, i2);
    ins3(e2, f2, d0, i0, d1, i1, d2v, i2);
  }
  if (j == 0) {
    float w0 = 1.f / (d0 + 1e-8f), w1 = 1.f / (d1 + 1e-8f), w2 = 1.f / (d2v + 1e-8f);
    float s = w0 + w1 + w2;
    size_t base = ((size_t)b * N_ + n) * 3;
    idx[base] = i0; idx[base + 1] = i1; idx[base + 2] = i2;
    wgt[base] = w0 / s; wgt[base + 1] = w1 / s; wgt[base + 2] = w2 / s;
  }
}

// interp -> xt[b][n][256:768] bf16; 8 points/block, 32 lanes each, float4 gathers
__global__ __launch_bounds__(256) void k_interp(const float* __restrict__ kft, const int* __restrict__ idx,
                                                const float* __restrict__ wgt, unsigned short* __restrict__ xt) {
  int pb = blockIdx.x * 8 + (threadIdx.x >> 5);
  int lane = threadIdx.x & 31;
  int b = pb >> 13;
  size_t t3 = (size_t)pb * 3;
  int i0 = idx[t3], i1 = idx[t3 + 1], i2 = idx[t3 + 2];
  float w0 = wgt[t3], w1 = wgt[t3 + 1], w2 = wgt[t3 + 2];
  const f32x4* f0 = (const f32x4*)(kft + ((size_t)b * M_ + i0) * C2_);
  const f32x4* f1 = (const f32x4*)(kft + ((size_t)b * M_ + i1) * C2_);
  const f32x4* f2 = (const f32x4*)(kft + ((size_t)b * M_ + i2) * C2_);
  unsigned short* o = xt + (size_t)pb * CIN_ + C1_;
#pragma unroll
  for (int k = 0; k < 4; ++k) {
    int c4 = lane + 32 * k;
    f32x4 a = f0[c4], bb = f1[c4], cc = f2[c4];
    u16x4 r;
#pragma unroll
    for (int e = 0; e < 4; ++e) r[e] = f2bf(w0 * a[e] + w1 * bb[e] + w2 * cc[e]);
    *(u16x4*)(o + 4 * c4) = r;
  }
}

// ---------------- bf16 MFMA GEMM, 2-phase double-buffered (T3-minimum) ----------------
// C(256 x 8192) = A(256 x K) * X^T, X point-major (N x K).
// 128x128 tile, BK=64, 4 waves (2x2), wave tile 64x64. LDS = 2 buffers x (A 16K + B 16K) = 64 KB.
// Schedule per K-step: STAGE(kt+1 -> buf^1) || COMPUTE(buf) ; ONE barrier (drains vmcnt+lgkm).
// Memory latency of kt+1 hides under the 64-MFMA cluster of kt.   [T3 2-phase, m248-verified form]
// LDS XOR swizzle via pre-swizzled GLOBAL source (rule 21) + same XOR on ds_read. 0 conflicts (R5).
// BN=true: B reg-staged, fused scale/shift+ReLU (scale/shift read from global, L1-cached).
// Epilogue: per-block partial BN stats to unique slots (no atomics, R5 lesson), then
// LDS-transpose store: all global C stores are 256-B contiguous row segments
// (fixes 2.3x write amplification seen on channel-major 2-B scatter, R5 Dispatch 46).

template <int K, int EPI, bool BN>
__global__ __launch_bounds__(256) void gemm_bt(const unsigned short* __restrict__ A,
                                               const unsigned short* __restrict__ Bm,
                                               unsigned short* __restrict__ C,
                                               float* __restrict__ psum, float* __restrict__ psq,
                                               const float* __restrict__ scale,
                                               const float* __restrict__ shift) {
  __shared__ __align__(16) char lds[65536];   // buf0: A[0,16K) B[16K,32K); buf1: +32K
  const int tid = threadIdx.x;
  const int l = tid & 63;
  const int wv = tid >> 6;
  const int wr = wv >> 1, wc = wv & 1;
  const int b = blockIdx.z;
  const int o0 = blockIdx.y * 128;
  const int n0 = blockIdx.x * 128;
  const char* Ab = (const char*)A + (size_t)o0 * (K * 2);
  const char* Bb = (const char*)Bm + ((size_t)b * N_ + n0) * (K * 2);

  f32x4 zero = {0.f, 0.f, 0.f, 0.f};
  f32x4 acc[4][4];
#pragma unroll
  for (int i = 0; i < 4; ++i)
#pragma unroll
    for (int j = 0; j < 4; ++j) acc[i][j] = zero;

  // gload geometry: wave wv stages rows [wv*32, wv*32+32), 4 instr x (8 rows = 1 KiB).
  // Linear LDS dest; pre-swizzled global col (involution ((l&7)^(l>>3))*16).
  const int grow = wv * 32 + (l >> 3);
  const int gcol = (((l & 7) ^ (l >> 3)) * 16);
  // reg-staging geometry (BN path): 4 chunks of 16B per thread over 128 rows
  int srow[4], scol[4];
#pragma unroll
  for (int i = 0; i < 4; ++i) { int q = tid + i * 256; srow[i] = q >> 3; scol[i] = (q & 7) * 16; }

  // BN: apply y1-BN+ReLU while writing B chunks to swizzled LDS
  auto bnwrite = [&](bf16x8* rb, int ktv, char* dstbase) {
#pragma unroll
    for (int i = 0; i < 4; ++i) {
      u16x8 v = *(u16x8*)&rb[i];
      int c0 = ktv * 64 + (scol[i] >> 1);
      f32x4 sa = *(const f32x4*)(scale + c0), sb = *(const f32x4*)(scale + c0 + 4);
      f32x4 ha = *(const f32x4*)(shift + c0), hb = *(const f32x4*)(shift + c0 + 4);
      u16x8 r;
#pragma unroll
      for (int e = 0; e < 4; ++e) {
        r[e]     = f2bf(fmaxf(bf2f(v[e])     * sa[e] + ha[e], 0.f));
        r[e + 4] = f2bf(fmaxf(bf2f(v[e + 4]) * sb[e] + hb[e], 0.f));
      }
      *(u16x8*)(dstbase + srow[i] * 128 + (scol[i] ^ ((srow[i] & 7) << 4))) = r;
    }
  };

  // ---- prologue: stage kt=0 into buffer 0
  if (BN) {
    bf16x8 rb0[4];
#pragma unroll
    for (int i = 0; i < 4; ++i)
      rb0[i] = *(const bf16x8*)(Bb + (size_t)srow[i] * (K * 2) + scol[i]);
#pragma unroll
    for (int i = 0; i < 4; ++i)
      gload16(Ab + (size_t)(grow + i * 8) * (K * 2) + gcol, lds + wv * 4096 + i * 1024);
    bnwrite(rb0, 0, lds + 16384);
  } else {
#pragma unroll
    for (int i = 0; i < 4; ++i) {
      int r = grow + i * 8;
      gload16(Ab + (size_t)r * (K * 2) + gcol, lds + wv * 4096 + i * 1024);
      gload16(Bb + (size_t)r * (K * 2) + gcol, lds + 16384 + wv * 4096 + i * 1024);
    }
  }
  __syncthreads();

  // ---- main loop: one barrier per K-step
  const int NK = K / 64;
  int cur = 0;
  for (int kt = 0; kt < NK; ++kt) {
    const bool haveNext = (kt + 1 < NK);
    bf16x8 rb2[4];
    if (haveNext) {
      char* nb = lds + (cur ^ 1) * 32768;
      if (BN) {
        const char* Bk = Bb + (size_t)(kt + 1) * 128;
#pragma unroll
        for (int i = 0; i < 4; ++i)
          rb2[i] = *(const bf16x8*)(Bk + (size_t)srow[i] * (K * 2) + scol[i]);
#pragma unroll
        for (int i = 0; i < 4; ++i)
          gload16(Ab + (size_t)(grow + i * 8) * (K * 2) + (kt + 1) * 128 + gcol,
                  nb + wv * 4096 + i * 1024);
      } else {
#pragma unroll
        for (int i = 0; i < 4; ++i) {
          int r = grow + i * 8;
          gload16(Ab + (size_t)r * (K * 2) + (kt + 1) * 128 + gcol, nb + wv * 4096 + i * 1024);
          gload16(Bb + (size_t)r * (K * 2) + (kt + 1) * 128 + gcol, nb + 16384 + wv * 4096 + i * 1024);
        }
      }
    }
    // compute on buf[cur]
    const char* base = lds + cur * 32768;
#pragma unroll
    for (int kk = 0; kk < 2; ++kk) {
      bf16x8 af[4], bfr[4];
#pragma unroll
      for (int mi = 0; mi < 4; ++mi) {
        int row = wr * 64 + mi * 16 + (l & 15);
        int cb = (kk * 64 + ((l >> 4) * 16)) ^ ((row & 7) << 4);
        af[mi] = *(const bf16x8*)(base + row * 128 + cb);
      }
#pragma unroll
      for (int ni = 0; ni < 4; ++ni) {
        int row = wc * 64 + ni * 16 + (l & 15);
        int cb = (kk * 64 + ((l >> 4) * 16)) ^ ((row & 7) << 4);
        bfr[ni] = *(const bf16x8*)(base + 16384 + row * 128 + cb);
      }
#pragma unroll
      for (int mi = 0; mi < 4; ++mi)
#pragma unroll
        for (int ni = 0; ni < 4; ++ni)
          acc[mi][ni] = __builtin_amdgcn_mfma_f32_16x16x32_bf16(af[mi], bfr[ni], acc[mi][ni], 0, 0, 0);
    }
    if (BN && haveNext) bnwrite(rb2, kt + 1, lds + (cur ^ 1) * 32768 + 16384);
    __syncthreads();   // drains vmcnt (next-tile gloads) + lgkm (frag reads, BN writes)
    cur ^= 1;
  }

  // ---- partial BN stats: reduce over n within wave, unique slot per (block, wc) — no atomics
  const int slot = (blockIdx.z * 64 + blockIdx.x) * 2 + wc;   // [0, 1024)
#pragma unroll
  for (int mi = 0; mi < 4; ++mi) {
    float s[4] = {0.f, 0.f, 0.f, 0.f}, q[4] = {0.f, 0.f, 0.f, 0.f};
#pragma unroll
    for (int ni = 0; ni < 4; ++ni)
#pragma unroll
      for (int r = 0; r < 4; ++r) { float v = acc[mi][ni][r]; s[r] += v; q[r] = fmaf(v, v, q[r]); }
#pragma unroll
    for (int m = 1; m <= 8; m <<= 1)
#pragma unroll
      for (int r = 0; r < 4; ++r) { s[r] += __shfl_xor(s[r], m); q[r] += __shfl_xor(q[r], m); }
    if ((l & 15) == 0) {
      int o = o0 + wr * 64 + mi * 16 + ((l >> 4) << 2);
#pragma unroll
      for (int r = 0; r < 4; ++r) {
        psum[(size_t)(o + r) * 1024 + slot] = s[r];
        psq [(size_t)(o + r) * 1024 + slot] = q[r];
      }
    }
  }

  // ---- transposing epilogue: acc -> LDS tile [128][144 u16] -> 256-B contiguous stores
  // (loop's final barrier already guarantees LDS is dead; frag map col(n)=l&15, row(o)=(l>>4)*4+r)
  unsigned short* t16 = (unsigned short*)lds;
#pragma unroll
  for (int mi = 0; mi < 4; ++mi) {
    int ol = wr * 64 + mi * 16 + ((l >> 4) << 2);
#pragma unroll
    for (int ni = 0; ni < 4; ++ni) {
      int nl = wc * 64 + ni * 16 + (l & 15);
#pragma unroll
      for (int r = 0; r < 4; ++r) {
        unsigned short v = f2bf(acc[mi][ni][r]);
        if (EPI == 0) t16[nl * 144 + ol + r] = v;        // rows = points   (y1 point-major)
        else          t16[(ol + r) * 144 + nl] = v;      // rows = channels (y2 channel-major)
      }
    }
  }
  __syncthreads();
#pragma unroll
  for (int t = 0; t < 8; ++t) {
    int row = wv * 32 + (l >> 4) + t * 4;
    u16x8 v = *(const u16x8*)(t16 + row * 144 + (l & 15) * 8);
    if (EPI == 0)
      *(u16x8*)(C + ((size_t)b * N_ + n0 + row) * 256 + o0 + (l & 15) * 8) = v;
    else
      *(u16x8*)(C + ((size_t)b * 256 + o0 + row) * N_ + n0 + (l & 15) * 8) = v;
  }
}

// ---------------- BN finalize: reduce 1024 partials per channel, compute scale/shift ----------------

__global__ __launch_bounds__(256) void k_finalize(const float* __restrict__ psum,
                                                  const float* __restrict__ psq,
                                                  const float* __restrict__ g,
                                                  const float* __restrict__ bb,
                                                  float* __restrict__ scale,
                                                  float* __restrict__ shift) {
  int c = blockIdx.x;
  const float* ps = psum + (size_t)c * 1024;
  const float* pq = psq + (size_t)c * 1024;
  float s = 0.f, q = 0.f;
#pragma unroll
  for (int k = 0; k < 4; ++k) { s += ps[threadIdx.x + 256 * k]; q += pq[threadIdx.x + 256 * k]; }
#pragma unroll
  for (int off = 32; off; off >>= 1) { s += __shfl_down(s, off); q += __shfl_down(q, off); }
  __shared__ float rs[4], rq[4];
  if ((threadIdx.x & 63) == 0) { rs[threadIdx.x >> 6] = s; rq[threadIdx.x >> 6] = q; }
  __syncthreads();
  if (threadIdx.x == 0) {
    float S = rs[0] + rs[1] + rs[2] + rs[3];
    float Q = rq[0] + rq[1] + rq[2] + rq[3];
    const float inv_n = 1.f / 65536.f;
    float mean = S * inv_n;
    float var = Q * inv_n - mean * mean;
    float rstd = rsqrtf(var + 1e-5f);
    float sc = g[c] * rstd;
    scale[c] = sc;
    shift[c] = bb[c] - mean * sc;
  }
}

// BN+ReLU on channel-major bf16 -> fp32 d_out
__global__ void k_bnrelu_out(const unsigned short* __restrict__ y, const float* __restrict__ scale,
                             const float* __restrict__ shift, float* __restrict__ out) {
  size_t i = ((size_t)blockIdx.x * 256 + threadIdx.x) * 4;
  int c = (int)((i >> 13) & 255);
  float sc = scale[c], sh = shift[c];
  u16x4 v = *(const u16x4*)(y + i);
  f32x4 o;
#pragma unroll
  for (int k = 0; k < 4; ++k) o[k] = fmaxf(bf2f(v[k]) * sc + sh, 0.f);
  *(f32x4*)(out + i) = o;
}

// ---------------- launch ----------------

extern "C" void kernel_launch(void* const* d_in, const int* in_sizes, int n_in,
                              void* d_out, int out_size, void* d_ws, size_t ws_size,
                              hipStream_t stream) {
  const float* unknown = (const float*)d_in[0];
  const float* known   = (const float*)d_in[1];
  const float* uf      = (const float*)d_in[2];
  const float* kf      = (const float*)d_in[3];
  const float* W1      = (const float*)d_in[4];
  const float* g1      = (const float*)d_in[5];
  const float* b1      = (const float*)d_in[6];
  const float* W2      = (const float*)d_in[7];
  const float* g2      = (const float*)d_in[8];
  const float* b2      = (const float*)d_in[9];
  float* out = (float*)d_out;

  char* ws = (char*)d_ws;
  unsigned short* xt  = (unsigned short*)(ws);                    // (B,N,768) bf16   100,663,296 B
  unsigned short* y1  = (unsigned short*)(ws + 100663296);        // (B,N,256) bf16    33,554,432 B
  unsigned short* y2  = (unsigned short*)(ws + 134217728);        // (B,256,N) bf16    33,554,432 B
  float*          kft = (float*)(ws + 167772160);                 // (B,M,512) f32     16,777,216 B
  // psum/psq alias kft's region: kft is dead after k_interp; both gemms reuse sequentially
  float*          psum = (float*)(ws + 167772160);                // 256*1024 f32       1,048,576 B
  float*          psq  = (float*)(ws + 168820736);                // 256*1024 f32       1,048,576 B
  unsigned short* w1b = (unsigned short*)(ws + 184549376);        //                      393,216 B
  unsigned short* w2b = (unsigned short*)(ws + 184942592);        //                      131,072 B
  int*            idx = (int*)(ws + 185073664);                   //                      786,432 B
  float*          wgt = (float*)(ws + 185860096);                 //                      786,432 B
  float*          st  = (float*)(ws + 186646528);                 // sc/sh block            4,096 B
  float *sc1 = st, *sh1 = st + 256, *sc2 = st + 512, *sh2 = st + 768;

  k_cast<<<768, 256, 0, stream>>>(W1, w1b, CMID_ * CIN_);
  k_cast<<<256, 256, 0, stream>>>(W2, w2b, COUT_ * CMID_);
  k_tr_kf<<<dim3(16, 32, B_), dim3(32, 8), 0, stream>>>(kf, kft);
  k_tr_uf<<<dim3(8, 256, B_), dim3(32, 8), 0, stream>>>(uf, xt);
  k_three_nn<<<B_ * 256, 256, 0, stream>>>(unknown, known, idx, wgt);
  k_interp<<<B_ * N_ / 8, 256, 0, stream>>>(kft, idx, wgt, xt);
  gemm_bt<CIN_, 0, false><<<dim3(64, 2, B_), 256, 0, stream>>>(w1b, xt, y1, psum, psq, nullptr, nullptr);
  k_finalize<<<256, 256, 0, stream>>>(psum, psq, g1, b1, sc1, sh1);
  gemm_bt<CMID_, 1, true><<<dim3(64, 2, B_), 256, 0, stream>>>(w2b, y1, y2, psum, psq, sc1, sh1);
  k_finalize<<<256, 256, 0, stream>>>(psum, psq, g2, b2, sc2, sh2);
  k_bnrelu_out<<<16384, 256, 0, stream>>>(y2, sc2, sh2, out);
}